// Round 1
// baseline (3403.674 us; speedup 1.0000x reference)
//
#include <hip/hip_runtime.h>
#include <stdint.h>

#define TPB 128

__device__ __forceinline__ float sigf(float x){
  return __builtin_amdgcn_rcpf(1.0f + __expf(-x));
}
__device__ __forceinline__ float tanh_f(float x){
  return 1.0f - 2.0f*__builtin_amdgcn_rcpf(1.0f + __expf(2.0f*x));
}

// ---------------- CSR build ----------------
__global__ void k_deg(const int* __restrict__ dst, int* __restrict__ deg, int E){
  int i = blockIdx.x*256 + threadIdx.x;
  if (i < E) atomicAdd(&deg[dst[i]], 1);
}

__global__ __launch_bounds__(256) void k_scan1(const int* __restrict__ deg, int* __restrict__ indptr,
                                               int* __restrict__ bsum, int N){
  __shared__ int s[256];
  int tid = threadIdx.x;
  int i = blockIdx.x*256 + tid;
  int v = (i < N) ? deg[i] : 0;
  s[tid] = v; __syncthreads();
  for (int off=1; off<256; off<<=1){
    int t = (tid>=off) ? s[tid-off] : 0;
    __syncthreads();
    s[tid] += t;
    __syncthreads();
  }
  if (i < N) indptr[i] = s[tid] - v;      // block-local exclusive
  if (tid == 255) bsum[blockIdx.x] = s[255];
}

__global__ __launch_bounds__(512) void k_scan2(const int* __restrict__ bsum, int* __restrict__ boffs,
                                               int* __restrict__ indptr, int nb, int N){
  __shared__ int s[512];
  int tid = threadIdx.x;
  int v = (tid < nb) ? bsum[tid] : 0;
  s[tid] = v; __syncthreads();
  for (int off=1; off<512; off<<=1){
    int t = (tid>=off) ? s[tid-off] : 0;
    __syncthreads();
    s[tid] += t;
    __syncthreads();
  }
  boffs[tid] = s[tid] - v;
  if (tid == nb-1) indptr[N] = s[tid];
}

__global__ __launch_bounds__(256) void k_scan3(int* __restrict__ indptr, const int* __restrict__ boffs, int N){
  int i = blockIdx.x*256 + threadIdx.x;
  if (i < N) indptr[i] += boffs[blockIdx.x];
}

__global__ void k_fill(const int* __restrict__ src, const int* __restrict__ dst,
                       const int* __restrict__ indptr, int* __restrict__ fill,
                       int* __restrict__ col, int E){
  int i = blockIdx.x*256 + threadIdx.x;
  if (i < E){
    int d = dst[i];
    int r = atomicAdd(&fill[d], 1);
    col[indptr[d] + r] = src[i];
  }
}

// ---------------- aggregation: z[n] = h[n] + sum_{neighbors} h[src] ----------------
template<int F>
__global__ __launch_bounds__(256) void k_agg(const float* __restrict__ h, const int* __restrict__ indptr,
                                             const int* __restrict__ col, float* __restrict__ z, int N){
  constexpr int TPN = F/4;          // threads per node
  constexpr int NPB = 256/TPN;      // nodes per block
  int n = blockIdx.x*NPB + threadIdx.x/TPN;
  int lane = threadIdx.x % TPN;
  if (n >= N) return;
  const float4* hv = (const float4*)h;
  float4 acc = hv[(size_t)n*TPN + lane];
  int s = indptr[n], e = indptr[n+1];
  for (int p = s; p < e; ++p){
    int c = col[p];
    float4 x = hv[(size_t)c*TPN + lane];
    acc.x += x.x; acc.y += x.y; acc.z += x.z; acc.w += x.w;
  }
  ((float4*)z)[(size_t)n*TPN + lane] = acc;
}

// ---------------- generic f32 GEMM: out[n][j] = act(sum_k A[n][k]*W[j][k] + b[j]) ----------------
// 64-node tile, 32-col chunks, 4x4 micro-tile, As [K][68], Ws [K][34] in LDS.
__global__ __launch_bounds__(TPB) void k_gemm(const float* __restrict__ A, const float* __restrict__ W,
                                              const float* __restrict__ bias, float* __restrict__ out,
                                              int K, int JC, int act, int N){
  extern __shared__ float sm[];
  float* As = sm;                       // [K][68]
  float* Ws = sm + (size_t)K*68;        // [K][34]
  const int tid = threadIdx.x;
  const int tx = tid & 15, ty = tid >> 4;
  const int nb = blockIdx.x * 64;
  const int kq = K >> 2;
  // stage A tile (lane-fast over nodes -> conflict-free LDS writes)
  for (int it = 0, idx = tid; it < (kq >> 1); ++it, idx += TPB){
    int nl = idx & 63, kk = idx >> 6;
    int k4 = kk << 2;
    int n = nb + nl;
    float4 v = make_float4(0.f,0.f,0.f,0.f);
    if (n < N) v = *(const float4*)(A + (size_t)n*K + k4);
    As[(size_t)(k4+0)*68 + nl] = v.x;
    As[(size_t)(k4+1)*68 + nl] = v.y;
    As[(size_t)(k4+2)*68 + nl] = v.z;
    As[(size_t)(k4+3)*68 + nl] = v.w;
  }
  const int ncc = JC >> 5;
  for (int cc = 0; cc < ncc; ++cc){
    __syncthreads();
    for (int it = 0, idx = tid; it < (kq >> 2); ++it, idx += TPB){
      int cl = idx & 31, kk = idx >> 5;
      int k4 = kk << 2;
      int j = (cc << 5) + cl;
      float4 v = *(const float4*)(W + (size_t)j*K + k4);
      Ws[(size_t)(k4+0)*34 + cl] = v.x;
      Ws[(size_t)(k4+1)*34 + cl] = v.y;
      Ws[(size_t)(k4+2)*34 + cl] = v.z;
      Ws[(size_t)(k4+3)*34 + cl] = v.w;
    }
    __syncthreads();
    float4 acc0 = make_float4(0,0,0,0), acc1 = acc0, acc2 = acc0, acc3 = acc0;
    #pragma unroll 4
    for (int k = 0; k < K; ++k){
      float4 a = *(const float4*)(As + (size_t)k*68 + (tx<<2));
      float2 w01 = *(const float2*)(Ws + (size_t)k*34 + (ty<<2));
      float2 w23 = *(const float2*)(Ws + (size_t)k*34 + (ty<<2) + 2);
      acc0.x = fmaf(a.x, w01.x, acc0.x); acc0.y = fmaf(a.x, w01.y, acc0.y);
      acc0.z = fmaf(a.x, w23.x, acc0.z); acc0.w = fmaf(a.x, w23.y, acc0.w);
      acc1.x = fmaf(a.y, w01.x, acc1.x); acc1.y = fmaf(a.y, w01.y, acc1.y);
      acc1.z = fmaf(a.y, w23.x, acc1.z); acc1.w = fmaf(a.y, w23.y, acc1.w);
      acc2.x = fmaf(a.z, w01.x, acc2.x); acc2.y = fmaf(a.z, w01.y, acc2.y);
      acc2.z = fmaf(a.z, w23.x, acc2.z); acc2.w = fmaf(a.z, w23.y, acc2.w);
      acc3.x = fmaf(a.w, w01.x, acc3.x); acc3.y = fmaf(a.w, w01.y, acc3.y);
      acc3.z = fmaf(a.w, w23.x, acc3.z); acc3.w = fmaf(a.w, w23.y, acc3.w);
    }
    int j0 = (cc << 5) + (ty << 2);
    float4 b4 = make_float4(0,0,0,0);
    if (bias) b4 = *(const float4*)(bias + j0);
    float4 r[4] = {acc0, acc1, acc2, acc3};
    #pragma unroll
    for (int i = 0; i < 4; ++i){
      int n = nb + (tx<<2) + i;
      if (n < N){
        float4 o;
        o.x = r[i].x + b4.x; o.y = r[i].y + b4.y; o.z = r[i].z + b4.z; o.w = r[i].w + b4.w;
        if (act){
          o.x = fmaxf(o.x, 0.f); o.y = fmaxf(o.y, 0.f);
          o.z = fmaxf(o.z, 0.f); o.w = fmaxf(o.w, 0.f);
        }
        *(float4*)(out + (size_t)n*JC + j0) = o;
      }
    }
  }
}

// ---------------- fused LSTM step ----------------
// Per block: 64 nodes. A = [seq_t (64) || h_prev (96)], W = [Wih || Whh] rows (384 x K).
// 12 chunks of (8 j x 4 gates). Gates fused in epilogue, h/c updated in place,
// alpha contribution (h . Watt[woff:woff+96]) reduced in-block.
__global__ __launch_bounds__(TPB) void k_lstm(const float* __restrict__ seq, float* __restrict__ hbuf,
                                              float* __restrict__ cbuf,
                                              const float* __restrict__ Wih, const float* __restrict__ Whh,
                                              const float* __restrict__ bih, const float* __restrict__ bhh,
                                              const float* __restrict__ Watt, const float* __restrict__ batt,
                                              float* __restrict__ alphaT, int first, int woff, int N){
  const int K = first ? 64 : 160;
  extern __shared__ float sm[];
  float* As = sm;                       // [K][68]
  float* Ws = sm + (size_t)K*68;        // [K][34]
  const int tid = threadIdx.x;
  const int tx = tid & 15, ty = tid >> 4;
  const int nb = blockIdx.x * 64;
  const int kq = K >> 2;
  for (int it = 0, idx = tid; it < (kq >> 1); ++it, idx += TPB){
    int nl = idx & 63, kk = idx >> 6;
    int k4 = kk << 2;
    int n = nb + nl;
    float4 v = make_float4(0.f,0.f,0.f,0.f);
    if (n < N){
      v = (k4 < 64) ? *(const float4*)(seq  + (size_t)n*64 + k4)
                    : *(const float4*)(hbuf + (size_t)n*96 + (k4-64));
    }
    As[(size_t)(k4+0)*68 + nl] = v.x;
    As[(size_t)(k4+1)*68 + nl] = v.y;
    As[(size_t)(k4+2)*68 + nl] = v.z;
    As[(size_t)(k4+3)*68 + nl] = v.w;
  }
  float aAcc[4] = {0.f,0.f,0.f,0.f};
  for (int cc = 0; cc < 12; ++cc){
    __syncthreads();
    // stage 32 cols = 8 j x 4 gates (col order: jl*4+gate)
    for (int it = 0, idx = tid; it < (kq >> 2); ++it, idx += TPB){
      int cl = idx & 31, kk = idx >> 5;
      int k4 = kk << 2;
      int jl = cl >> 2, g = cl & 3;
      int row = g*96 + cc*8 + jl;
      float4 v = (k4 < 64) ? *(const float4*)(Wih + (size_t)row*64 + k4)
                           : *(const float4*)(Whh + (size_t)row*96 + (k4-64));
      Ws[(size_t)(k4+0)*34 + cl] = v.x;
      Ws[(size_t)(k4+1)*34 + cl] = v.y;
      Ws[(size_t)(k4+2)*34 + cl] = v.z;
      Ws[(size_t)(k4+3)*34 + cl] = v.w;
    }
    __syncthreads();
    float4 acc0 = make_float4(0,0,0,0), acc1 = acc0, acc2 = acc0, acc3 = acc0;
    #pragma unroll 4
    for (int k = 0; k < K; ++k){
      float4 a = *(const float4*)(As + (size_t)k*68 + (tx<<2));
      float2 w01 = *(const float2*)(Ws + (size_t)k*34 + (ty<<2));
      float2 w23 = *(const float2*)(Ws + (size_t)k*34 + (ty<<2) + 2);
      acc0.x = fmaf(a.x, w01.x, acc0.x); acc0.y = fmaf(a.x, w01.y, acc0.y);
      acc0.z = fmaf(a.x, w23.x, acc0.z); acc0.w = fmaf(a.x, w23.y, acc0.w);
      acc1.x = fmaf(a.y, w01.x, acc1.x); acc1.y = fmaf(a.y, w01.y, acc1.y);
      acc1.z = fmaf(a.y, w23.x, acc1.z); acc1.w = fmaf(a.y, w23.y, acc1.w);
      acc2.x = fmaf(a.z, w01.x, acc2.x); acc2.y = fmaf(a.z, w01.y, acc2.y);
      acc2.z = fmaf(a.z, w23.x, acc2.z); acc2.w = fmaf(a.z, w23.y, acc2.w);
      acc3.x = fmaf(a.w, w01.x, acc3.x); acc3.y = fmaf(a.w, w01.y, acc3.y);
      acc3.z = fmaf(a.w, w23.x, acc3.z); acc3.w = fmaf(a.w, w23.y, acc3.w);
    }
    int j = cc*8 + ty;
    float bI = bih[j]       + bhh[j];
    float bF = bih[96 + j]  + bhh[96 + j];
    float bG = bih[192 + j] + bhh[192 + j];
    float bO = bih[288 + j] + bhh[288 + j];
    float wa = Watt[woff + j];
    float4 accs[4] = {acc0, acc1, acc2, acc3};
    #pragma unroll
    for (int i = 0; i < 4; ++i){
      int n = nb + (tx<<2) + i;
      if (n < N){
        float gi = accs[i].x + bI;
        float gf = accs[i].y + bF;
        float gg = accs[i].z + bG;
        float go = accs[i].w + bO;
        float cp = first ? 0.f : cbuf[(size_t)n*96 + j];
        float c = sigf(gf)*cp + sigf(gi)*tanh_f(gg);
        float h = sigf(go)*tanh_f(c);
        cbuf[(size_t)n*96 + j] = c;
        hbuf[(size_t)n*96 + j] = h;
        aAcc[i] += h * wa;
      }
    }
  }
  __syncthreads();
  float* sA = Ws;   // reuse: need 8*68 floats
  sA[(size_t)ty*68 + (tx<<2) + 0] = aAcc[0];
  sA[(size_t)ty*68 + (tx<<2) + 1] = aAcc[1];
  sA[(size_t)ty*68 + (tx<<2) + 2] = aAcc[2];
  sA[(size_t)ty*68 + (tx<<2) + 3] = aAcc[3];
  __syncthreads();
  if (tid < 64){
    int n = nb + tid;
    if (n < N){
      float s = 0.f;
      #pragma unroll
      for (int r = 0; r < 8; ++r) s += sA[(size_t)r*68 + tid];
      if (woff == 0) alphaT[n] = batt[0] + s;
      else           alphaT[n] += s;
    }
  }
}

// ---------------- JK softmax + xjk + Wlin + Wfc1 + leaky ----------------
__global__ __launch_bounds__(256) void k_jk(const float* __restrict__ alpha,
                                            const float* __restrict__ h1, const float* __restrict__ h2,
                                            const float* __restrict__ h3,
                                            const float* __restrict__ Wlin, const float* __restrict__ blin,
                                            const float* __restrict__ Wfc1, const float* __restrict__ bfc1,
                                            float* __restrict__ vout, int N){
  __shared__ float sWl[64*65];
  __shared__ float sX[4][64];
  __shared__ float sR[4][64];
  int tid = threadIdx.x;
  for (int idx = tid; idx < 1024; idx += 256){
    int j = idx >> 4;
    int c4 = (idx & 15) << 2;
    float4 v = *(const float4*)(Wlin + (size_t)j*64 + c4);
    sWl[j*65 + c4+0] = v.x; sWl[j*65 + c4+1] = v.y;
    sWl[j*65 + c4+2] = v.z; sWl[j*65 + c4+3] = v.w;
  }
  int ln = tid >> 6, j = tid & 63;
  int n = blockIdx.x*4 + ln;
  bool ok = n < N;
  float xj = 0.f;
  if (ok){
    float a0 = alpha[n], a1 = alpha[(size_t)N + n], a2 = alpha[(size_t)2*N + n];
    float m = fmaxf(a0, fmaxf(a1, a2));
    float e0 = __expf(a0-m), e1 = __expf(a1-m), e2 = __expf(a2-m);
    float inv = __builtin_amdgcn_rcpf(e0+e1+e2);
    float w0 = e0*inv, w1 = e1*inv, w2 = e2*inv;
    xj = w0*h1[(size_t)n*64 + j] + w1*h2[(size_t)n*64 + j] + w2*h3[(size_t)n*64 + j];
  }
  sX[ln][j] = xj;
  __syncthreads();
  float acc = blin[j];
  #pragma unroll 8
  for (int c = 0; c < 64; ++c) acc = fmaf(sX[ln][c], sWl[j*65 + c], acc);
  sR[ln][j] = acc * Wfc1[j];
  __syncthreads();
  #pragma unroll
  for (int off = 32; off > 0; off >>= 1){
    if (j < off) sR[ln][j] += sR[ln][j + off];
    __syncthreads();
  }
  if (j == 0 && ok){
    float vv = sR[ln][0] + bfc1[0];
    vout[n] = vv >= 0.f ? vv : 0.01f*vv;
  }
}

// ---------------- final dot (deterministic two-stage, f64 accum) ----------------
__global__ __launch_bounds__(256) void k_final1(const float* __restrict__ w, const float* __restrict__ v,
                                                double* __restrict__ part, int N){
  __shared__ double sd[256];
  int tid = threadIdx.x;
  double a = 0.0;
  for (int i = blockIdx.x*256 + tid; i < N; i += 256*256)
    a += (double)(w[i] * v[i]);
  sd[tid] = a; __syncthreads();
  for (int off = 128; off > 0; off >>= 1){
    if (tid < off) sd[tid] += sd[tid + off];
    __syncthreads();
  }
  if (tid == 0) part[blockIdx.x] = sd[0];
}

__global__ __launch_bounds__(256) void k_final2(const double* __restrict__ part, const float* __restrict__ bfc2,
                                                float* __restrict__ out){
  __shared__ double sd[256];
  int tid = threadIdx.x;
  sd[tid] = part[tid]; __syncthreads();
  for (int off = 128; off > 0; off >>= 1){
    if (tid < off) sd[tid] += sd[tid + off];
    __syncthreads();
  }
  if (tid == 0) out[0] = (float)(sd[0] + (double)bfc2[0]);
}

// ---------------- host ----------------
extern "C" void kernel_launch(void* const* d_in, const int* in_sizes, int n_in,
                              void* d_out, int out_size, void* d_ws, size_t ws_size,
                              hipStream_t stream){
  const float* x    = (const float*)d_in[0];
  const int*   ei   = (const int*)d_in[1];
  const float* W0a  = (const float*)d_in[2];
  const float* b0a  = (const float*)d_in[3];
  const float* W0b  = (const float*)d_in[4];
  const float* b0b  = (const float*)d_in[5];
  const float* W1a  = (const float*)d_in[6];
  const float* b1a  = (const float*)d_in[7];
  const float* W1b  = (const float*)d_in[8];
  const float* b1b  = (const float*)d_in[9];
  const float* W2a  = (const float*)d_in[10];
  const float* b2a  = (const float*)d_in[11];
  const float* W2b  = (const float*)d_in[12];
  const float* b2b  = (const float*)d_in[13];
  const float* Wih_f = (const float*)d_in[14];
  const float* Whh_f = (const float*)d_in[15];
  const float* bih_f = (const float*)d_in[16];
  const float* bhh_f = (const float*)d_in[17];
  const float* Wih_b = (const float*)d_in[18];
  const float* Whh_b = (const float*)d_in[19];
  const float* bih_b = (const float*)d_in[20];
  const float* bhh_b = (const float*)d_in[21];
  const float* Watt = (const float*)d_in[22];
  const float* batt = (const float*)d_in[23];
  const float* Wlin = (const float*)d_in[24];
  const float* blin = (const float*)d_in[25];
  const float* Wfc1 = (const float*)d_in[26];
  const float* bfc1 = (const float*)d_in[27];
  const float* Wfc2 = (const float*)d_in[28];
  const float* bfc2 = (const float*)d_in[29];
  float* out = (float*)d_out;

  const int N = in_sizes[0] / 128;
  const int E = in_sizes[1] / 2;
  const int* src = ei;
  const int* dst = ei + E;

  uint8_t* w8 = (uint8_t*)d_ws;
  size_t off = 0;
  auto alloc = [&](size_t bytes) -> void* {
    void* p = w8 + off;
    off = (off + bytes + 255) & ~(size_t)255;
    return p;
  };
  int*    deg    = (int*)   alloc((size_t)N*4);
  int*    fill   = (int*)   alloc((size_t)N*4);
  int*    indptr = (int*)   alloc(((size_t)N+1)*4);
  int*    col    = (int*)   alloc((size_t)E*4);
  int*    bsum   = (int*)   alloc(2048);
  int*    boffs  = (int*)   alloc(2048);
  float*  h1     = (float*) alloc((size_t)N*64*4);
  float*  h2     = (float*) alloc((size_t)N*64*4);
  float*  h3     = (float*) alloc((size_t)N*64*4);
  float*  alpha  = (float*) alloc((size_t)3*N*4);
  float*  vbuf   = (float*) alloc((size_t)N*4);
  double* part   = (double*)alloc(256*8);
  float*  P      = (float*) alloc((size_t)N*192*4);   // phase-shared region
  if (off > ws_size) return;  // workspace too small: bail (will fail validation loudly)
  float* zbuf = P;                      // GIN phase: z tile [N,128] (or [N,64])
  float* mid  = P + (size_t)N*128;      // GIN phase: MLP intermediate [N,64]
  float* hb   = P;                      // LSTM phase: h [N,96]
  float* cb   = P + (size_t)N*96;       // LSTM phase: c [N,96]

  const size_t lds64  = 64  * 102 * 4;
  const size_t lds128 = 128 * 102 * 4;
  const size_t lds160 = 160 * 102 * 4;

  hipMemsetAsync(deg,  0, (size_t)N*4, stream);
  hipMemsetAsync(fill, 0, (size_t)N*4, stream);

  int gE = (E + 255) / 256;
  int nb1 = (N + 255) / 256;
  int gG = (N + 63) / 64;

  k_deg  <<<gE, 256, 0, stream>>>(dst, deg, E);
  k_scan1<<<nb1, 256, 0, stream>>>(deg, indptr, bsum, N);
  k_scan2<<<1, 512, 0, stream>>>(bsum, boffs, indptr, nb1, N);
  k_scan3<<<nb1, 256, 0, stream>>>(indptr, boffs, N);
  k_fill <<<gE, 256, 0, stream>>>(src, dst, indptr, fill, col, E);

  // ---- GIN layer 0 (F=128) ----
  k_agg<128><<<(N+7)/8, 256, 0, stream>>>(x, indptr, col, zbuf, N);
  k_gemm<<<gG, TPB, lds128, stream>>>(zbuf, W0a, b0a, mid, 128, 64, 1, N);
  k_gemm<<<gG, TPB, lds64,  stream>>>(mid,  W0b, b0b, h1,  64,  64, 1, N);
  // ---- GIN layer 1 ----
  k_agg<64><<<(N+15)/16, 256, 0, stream>>>(h1, indptr, col, zbuf, N);
  k_gemm<<<gG, TPB, lds64, stream>>>(zbuf, W1a, b1a, mid, 64, 64, 1, N);
  k_gemm<<<gG, TPB, lds64, stream>>>(mid,  W1b, b1b, h2,  64, 64, 1, N);
  // ---- GIN layer 2 ----
  k_agg<64><<<(N+15)/16, 256, 0, stream>>>(h2, indptr, col, zbuf, N);
  k_gemm<<<gG, TPB, lds64, stream>>>(zbuf, W2a, b2a, mid, 64, 64, 1, N);
  k_gemm<<<gG, TPB, lds64, stream>>>(mid,  W2b, b2b, h3,  64, 64, 1, N);

  // ---- LSTM forward (t = 0,1,2) ----
  k_lstm<<<gG, TPB, lds64,  stream>>>(h1, hb, cb, Wih_f, Whh_f, bih_f, bhh_f, Watt, batt,
                                      alpha,                1, 0, N);
  k_lstm<<<gG, TPB, lds160, stream>>>(h2, hb, cb, Wih_f, Whh_f, bih_f, bhh_f, Watt, batt,
                                      alpha + (size_t)N,    0, 0, N);
  k_lstm<<<gG, TPB, lds160, stream>>>(h3, hb, cb, Wih_f, Whh_f, bih_f, bhh_f, Watt, batt,
                                      alpha + (size_t)2*N,  0, 0, N);
  // ---- LSTM backward (t = 2,1,0) ----
  k_lstm<<<gG, TPB, lds64,  stream>>>(h3, hb, cb, Wih_b, Whh_b, bih_b, bhh_b, Watt, batt,
                                      alpha + (size_t)2*N,  1, 96, N);
  k_lstm<<<gG, TPB, lds160, stream>>>(h2, hb, cb, Wih_b, Whh_b, bih_b, bhh_b, Watt, batt,
                                      alpha + (size_t)N,    0, 96, N);
  k_lstm<<<gG, TPB, lds160, stream>>>(h1, hb, cb, Wih_b, Whh_b, bih_b, bhh_b, Watt, batt,
                                      alpha,                0, 96, N);

  // ---- JK attention + linear + fc1 + leaky ----
  k_jk<<<(N+3)/4, 256, 0, stream>>>(alpha, h1, h2, h3, Wlin, blin, Wfc1, bfc1, vbuf, N);

  // ---- final dot ----
  k_final1<<<256, 256, 0, stream>>>(Wfc2, vbuf, part, N);
  k_final2<<<1, 256, 0, stream>>>(part, bfc2, out);
}